// Round 7
// baseline (535.716 us; speedup 1.0000x reference)
//
#include <hip/hip_runtime.h>
#include <stdint.h>

#define NPTS 2048
#define SOUT 512
#define NB   2
#define TFPS 512           // 8 waves: waves 0-3 batch 0, waves 4-7 batch 1
#define PPT  8             // points per lane, k-major within each batch group
#define NW   4             // waves per batch group
#define T2   64

typedef float vf2 __attribute__((ext_vector_type(2)));

// ---- DPP wave64 max-reduce (nonneg values; bound_ctrl zero-fill is safe) ----
__device__ __forceinline__ float wave_allmax_f32(float v) {
    int x = __float_as_int(v); int t;
    t = __builtin_amdgcn_update_dpp(x, x, 0x111, 0xF, 0xF, true); v = fmaxf(v, __int_as_float(t)); x = __float_as_int(v);
    t = __builtin_amdgcn_update_dpp(x, x, 0x112, 0xF, 0xF, true); v = fmaxf(v, __int_as_float(t)); x = __float_as_int(v);
    t = __builtin_amdgcn_update_dpp(x, x, 0x114, 0xF, 0xF, true); v = fmaxf(v, __int_as_float(t)); x = __float_as_int(v);
    t = __builtin_amdgcn_update_dpp(x, x, 0x118, 0xF, 0xF, true); v = fmaxf(v, __int_as_float(t)); x = __float_as_int(v);
    t = __builtin_amdgcn_update_dpp(x, x, 0x142, 0xA, 0xF, true); v = fmaxf(v, __int_as_float(t)); x = __float_as_int(v);
    t = __builtin_amdgcn_update_dpp(x, x, 0x143, 0xC, 0xF, true); v = fmaxf(v, __int_as_float(t)); x = __float_as_int(v);
    return __int_as_float(__builtin_amdgcn_readlane(x, 63));
}
__device__ __forceinline__ float lane_bcast(float v, int l) {
    return __int_as_float(__builtin_amdgcn_readlane(__float_as_int(v), l));
}

// ---------------- Kernel 1: FPS, both batches fused in ONE block -------------
// 8 waves on one CU -> 2 waves/SIMD from INDEPENDENT serial chains (batch 0 &
// batch 1) co-issue, hiding barrier/LDS/DPP latency. Per-group structure is
// R6's validated one: k-major 8 pts/lane in registers, packed-f32 distance
// (contract off, bit-exact), coord-carrying local tree, DPP value max +
// ballot/ctz (lowest lane = lowest index), per-group 4-slot parity merge
// (ties -> lower wave = lower index). No sxyz LDS: init from global (96 B
// contiguous per lane), far centroid via uniform scalar load.
__global__ __launch_bounds__(TFPS, 1) void fps_kernel(const float* __restrict__ xyz,
                                                      float* __restrict__ new_xyz,
                                                      int far0, int far1) {
    __shared__ float4 slot[2][NB][NW];     // {val,x,y,z} parity-buffered per group
    __shared__ float  scf[NB][SOUT * 3];
    const int tid  = threadIdx.x;
    const int bg   = tid >> 8;             // batch group 0/1
    const int t    = tid & 255;            // thread within group
    const int lane = tid & 63;
    const int wvl  = (tid >> 6) & 3;       // wave within group
    const float* xb = xyz + (size_t)bg * NPTS * 3;

    // init: lane's 8 consecutive points = 96 contiguous bytes (16B-aligned)
    float v24[24];
    {
        const float4* src = (const float4*)(xb + t * PPT * 3);
#pragma unroll
        for (int j = 0; j < 6; ++j) {
            float4 a = src[j];
            v24[j*4+0] = a.x; v24[j*4+1] = a.y; v24[j*4+2] = a.z; v24[j*4+3] = a.w;
        }
    }
    vf2 PX[4], PY[4], PZ[4], DD[4];
#pragma unroll
    for (int j = 0; j < 4; ++j) {
        PX[j].x = v24[(2*j)*3+0]; PX[j].y = v24[(2*j+1)*3+0];
        PY[j].x = v24[(2*j)*3+1]; PY[j].y = v24[(2*j+1)*3+1];
        PZ[j].x = v24[(2*j)*3+2]; PZ[j].y = v24[(2*j+1)*3+2];
        DD[j].x = 1e10f; DD[j].y = 1e10f;
    }
    const int far = (bg == 0) ? far0 : far1;   // SGPR-uniform per group
    float cx = xb[far*3+0], cy = xb[far*3+1], cz = xb[far*3+2];

    for (int s = 0; s < SOUT; ++s) {
        if (t == 0) { scf[bg][s*3+0] = cx; scf[bg][s*3+1] = cy; scf[bg][s*3+2] = cz; }
        if (s == SOUT - 1) break;
        // packed distance update (each op separately rounded -> bit-exact)
        {
#pragma clang fp contract(off)
            vf2 vcx; vcx.x = cx; vcx.y = cx;
            vf2 vcy; vcy.x = cy; vcy.y = cy;
            vf2 vcz; vcz.x = cz; vcz.y = cz;
#pragma unroll
            for (int j = 0; j < 4; ++j) {
                vf2 dx = PX[j] - vcx;
                vf2 dy = PY[j] - vcy;
                vf2 dz = PZ[j] - vcz;
                vf2 d2 = (dx*dx + dy*dy) + dz*dz;   // ((xx+yy)+zz), rn each
                DD[j].x = fminf(DD[j].x, d2.x);
                DD[j].y = fminf(DD[j].y, d2.y);
            }
        }
        // local argmax over 8 pts, coords carried; left-if->= on contiguous
        // halves == first-occurrence (lowest index) tie-break
        float v1[4], x1v[4], y1v[4], z1v[4];
#pragma unroll
        for (int j = 0; j < 4; ++j) {
            bool l = DD[j].x >= DD[j].y;
            v1[j]  = l ? DD[j].x : DD[j].y;
            x1v[j] = l ? PX[j].x : PX[j].y;
            y1v[j] = l ? PY[j].x : PY[j].y;
            z1v[j] = l ? PZ[j].x : PZ[j].y;
        }
        float v2v[2], x2v[2], y2v[2], z2v[2];
#pragma unroll
        for (int j = 0; j < 2; ++j) {
            bool l = v1[2*j] >= v1[2*j+1];
            v2v[j] = l ? v1[2*j]  : v1[2*j+1];
            x2v[j] = l ? x1v[2*j] : x1v[2*j+1];
            y2v[j] = l ? y1v[2*j] : y1v[2*j+1];
            z2v[j] = l ? z1v[2*j] : z1v[2*j+1];
        }
        bool lf = v2v[0] >= v2v[1];
        float bv = lf ? v2v[0] : v2v[1];
        float bx = lf ? x2v[0] : x2v[1];
        float by = lf ? y2v[0] : y2v[1];
        float bz = lf ? z2v[0] : z2v[1];
        // wave winner: DPP value max; lowest tie lane = lowest index (k-major)
        float wmax = wave_allmax_f32(bv);
        unsigned long long msk = __ballot(bv == wmax);
        int l0 = (int)__builtin_ctzll(msk);
        float wx = lane_bcast(bx, l0);
        float wy = lane_bcast(by, l0);
        float wz = lane_bcast(bz, l0);
        const int par = s & 1;
        if (lane == 0) slot[par][bg][wvl] = make_float4(wmax, wx, wy, wz);
        __syncthreads();                   // block-wide: serves both groups
        float4 a0 = slot[par][bg][0];
        float bvv = a0.x; cx = a0.y; cy = a0.z; cz = a0.w;
#pragma unroll
        for (int w = 1; w < NW; ++w) {
            float4 aw = slot[par][bg][w];
            bool take = aw.x > bvv;        // tie -> lower wave = lower idx
            bvv = take ? aw.x : bvv;
            cx  = take ? aw.y : cx;
            cy  = take ? aw.z : cy;
            cz  = take ? aw.w : cz;
        }
    }
    __syncthreads();
    float* ob = new_xyz + (size_t)bg * SOUT * 3;
    for (int i = t; i < SOUT * 3; i += 256) ob[i] = scf[bg][i];
}

// ---------------- Kernel 2: radius group + MLP, TWO queries per wave ---------
// Grid 512 x 64. One wave handles queries q0=2*blk, q0+1 (always same batch).
// Scan shares the point loads between both queries and interleaves the two
// independent ballot/prefix chains (ILP fills the serial-compaction latency).
// w3-row registers + rb3 loaded once, reused. MLP per query sequential
// through the same sh2 (single wave -> DS in-order, no barriers).
__global__ __launch_bounds__(T2, 1) void group_mlp_kernel(
        const float* __restrict__ xyz,  const float* __restrict__ points,
        const float* __restrict__ w1,   const float* __restrict__ b1,
        const float* __restrict__ w2,   const float* __restrict__ b2,
        const float* __restrict__ w3,   const float* __restrict__ b3,
        const float* __restrict__ new_xyz, float* __restrict__ new_points) {
    __shared__ unsigned short sidx[2][NPTS];   // 8 KB
    __shared__ float sh2[64 * 36];             // 9 KB, 16B-aligned rows
    const int lane = threadIdx.x;

    float wf3[32];                             // lane's w3 row (lane = out ch)
    {
        const float4* w3v = (const float4*)(w3 + lane * 32);
#pragma unroll
        for (int j = 0; j < 8; ++j) {
            float4 v = w3v[j];
            wf3[j*4+0] = v.x; wf3[j*4+1] = v.y; wf3[j*4+2] = v.z; wf3[j*4+3] = v.w;
        }
    }
    const float rb3 = b3[lane];

    const int q0 = blockIdx.x * 2;
    const int b  = q0 >> 9;
    const float* xb = xyz    + (size_t)b * NPTS * 3;
    const float* pb = points + (size_t)b * 13 * NPTS;
    const float q0x = new_xyz[q0*3+0], q0y = new_xyz[q0*3+1], q0z = new_xyz[q0*3+2];
    const float q1x = new_xyz[q0*3+3], q1y = new_xyz[q0*3+4], q1z = new_xyz[q0*3+5];
    const float q0s = __fadd_rn(__fadd_rn(__fmul_rn(q0x,q0x), __fmul_rn(q0y,q0y)), __fmul_rn(q0z,q0z));
    const float q1s = __fadd_rn(__fadd_rn(__fmul_rn(q1x,q1x), __fmul_rn(q1y,q1y)), __fmul_rn(q1z,q1z));

    // dual scan: one point load, two predicates, two independent compactions
    int cnt0 = 0, cnt1 = 0;
    const unsigned long long lm = (1ull << lane) - 1ull;
    for (int r = 0; r < NPTS / T2; ++r) {
        int n = r * T2 + lane;
        float x = xb[n*3+0], y = xb[n*3+1], z = xb[n*3+2];
        float pn = __fadd_rn(__fadd_rn(__fmul_rn(x,x), __fmul_rn(y,y)), __fmul_rn(z,z));
        float dt0 = __fadd_rn(__fadd_rn(__fmul_rn(q0x,x), __fmul_rn(q0y,y)), __fmul_rn(q0z,z));
        float dt1 = __fadd_rn(__fadd_rn(__fmul_rn(q1x,x), __fmul_rn(q1y,y)), __fmul_rn(q1z,z));
        float s0 = __fsub_rn(__fadd_rn(q0s, pn), __fmul_rn(2.0f, dt0));
        float s1 = __fsub_rn(__fadd_rn(q1s, pn), __fmul_rn(2.0f, dt1));
        bool sel0 = !(s0 > 0.04f);
        bool sel1 = !(s1 > 0.04f);
        unsigned long long m0 = __ballot(sel0);
        unsigned long long m1 = __ballot(sel1);
        if (sel0) sidx[0][cnt0 + __popcll(m0 & lm)] = (unsigned short)n;
        if (sel1) sidx[1][cnt1 + __popcll(m1 & lm)] = (unsigned short)n;
        cnt0 += (int)__popcll(m0);
        cnt1 += (int)__popcll(m1);
    }

    // per-query MLP: L1/L2 lane=neighbor (uniform weight rows -> s_load);
    // L3 via sh2 transpose, lane=channel, rows capped at valid count.
#pragma unroll 1
    for (int qi = 0; qi < 2; ++qi) {
        const unsigned short* si = sidx[qi];
        const int K = qi ? cnt1 : cnt0;             // >= 1 (query's own point)
        const float qx = qi ? q1x : q0x;
        const float qy = qi ? q1y : q0y;
        const float qz = qi ? q1z : q0z;
        const int nfirst = (int)si[0];
        float mx = -3.0e38f;
        for (int tb = 0; tb < K; tb += T2) {
            int m = tb + lane;
            int n = (m < K) ? (int)si[m] : nfirst;  // pad = first neighbor
            float f[16];
            f[0] = xb[n*3+0] - qx;
            f[1] = xb[n*3+1] - qy;
            f[2] = xb[n*3+2] - qz;
#pragma unroll
            for (int c = 0; c < 13; ++c) f[3+c] = pb[c*NPTS + n];
            float h1[32];
#pragma unroll
            for (int o = 0; o < 32; ++o) {
                float acc = b1[o];                  // uniform -> s_load
                const float4* wr = (const float4*)(w1 + o*16);
#pragma unroll
                for (int c4 = 0; c4 < 4; ++c4) {
                    float4 wv = wr[c4];
                    acc = fmaf(f[c4*4+0], wv.x, acc);
                    acc = fmaf(f[c4*4+1], wv.y, acc);
                    acc = fmaf(f[c4*4+2], wv.z, acc);
                    acc = fmaf(f[c4*4+3], wv.w, acc);
                }
                h1[o] = fmaxf(acc, 0.0f);
            }
            float h2[32];
#pragma unroll
            for (int o = 0; o < 32; ++o) {
                float acc = b2[o];                  // uniform -> s_load
                const float4* wr = (const float4*)(w2 + o*32);
#pragma unroll
                for (int c4 = 0; c4 < 8; ++c4) {
                    float4 wv = wr[c4];
                    acc = fmaf(h1[c4*4+0], wv.x, acc);
                    acc = fmaf(h1[c4*4+1], wv.y, acc);
                    acc = fmaf(h1[c4*4+2], wv.z, acc);
                    acc = fmaf(h1[c4*4+3], wv.w, acc);
                }
                h2[o] = fmaxf(acc, 0.0f);
            }
            {
                float4* row = (float4*)(sh2 + lane * 36);
#pragma unroll
                for (int c4 = 0; c4 < 8; ++c4)
                    row[c4] = make_float4(h2[c4*4+0], h2[c4*4+1], h2[c4*4+2], h2[c4*4+3]);
            }
            int rows = K - tb; if (rows > T2) rows = T2;
#pragma unroll 4
            for (int n2 = 0; n2 < rows; ++n2) {
                const float4* hr = (const float4*)(sh2 + n2 * 36);
                float acc = rb3;
#pragma unroll
                for (int c4 = 0; c4 < 8; ++c4) {
                    float4 h = hr[c4];
                    acc = fmaf(h.x, wf3[c4*4+0], acc);
                    acc = fmaf(h.y, wf3[c4*4+1], acc);
                    acc = fmaf(h.z, wf3[c4*4+2], acc);
                    acc = fmaf(h.w, wf3[c4*4+3], acc);
                }
                mx = fmaxf(mx, acc);
            }
            // single wave: DS ops in-order -> no barrier between chunks
        }
        const int s = (q0 + qi) & (SOUT - 1);
        new_points[((size_t)b * 64 + lane) * SOUT + s] = mx;   // (B, 64, S)
    }
}

// ---------------- host: threefry2x32 (JAX key(42) randint seed) --------------
static inline uint32_t rotl32(uint32_t x, int r) { return (x << r) | (x >> (32 - r)); }
static void threefry2x32_host(uint32_t k0, uint32_t k1, uint32_t& x0, uint32_t& x1) {
    const int R[2][4] = {{13,15,26,6},{17,29,16,24}};
    uint32_t ks[3] = {k0, k1, k0 ^ k1 ^ 0x1BD11BDAu};
    x0 += ks[0]; x1 += ks[1];
    for (int i = 0; i < 5; ++i) {
        for (int j = 0; j < 4; ++j) { x0 += x1; x1 = rotl32(x1, R[i & 1][j]); x1 ^= x0; }
        x0 += ks[(i + 1) % 3];
        x1 += ks[(i + 2) % 3] + (uint32_t)(i + 1);
    }
}

extern "C" void kernel_launch(void* const* d_in, const int* in_sizes, int n_in,
                              void* d_out, int out_size, void* d_ws, size_t ws_size,
                              hipStream_t stream) {
    const float* xyz    = (const float*)d_in[0];
    const float* points = (const float*)d_in[1];
    const float* w1 = (const float*)d_in[2];
    const float* b1 = (const float*)d_in[3];
    const float* w2 = (const float*)d_in[4];
    const float* b2 = (const float*)d_in[5];
    const float* w3 = (const float*)d_in[6];
    const float* b3 = (const float*)d_in[7];
    float* out        = (float*)d_out;
    float* new_xyz    = out;                      // (B, S, 3)
    float* new_points = out + NB * SOUT * 3;      // (B, 64, S)

    // jax.random.randint(key(42), (2,), 0, 2048), modern JAX
    // (jax_threefry_partitionable=True): _randint splits the key first:
    //   k1, k2 = split(key); result = random_bits(k2, 32, (2,)) & 2047
    // foldlike split: k2 = threefry((0,42),(0,1)) full pair.
    // partitionable bits: elem i = xor-halves of threefry(k2, (0,i)).
    // (VERIFIED passing in rounds 3-6 — do not change.)
    uint32_t k2a = 0, k2b = 1; threefry2x32_host(0u, 42u, k2a, k2b);
    uint32_t u0 = 0, u1 = 0;  threefry2x32_host(k2a, k2b, u0, u1);
    uint32_t v0 = 0, v1 = 1;  threefry2x32_host(k2a, k2b, v0, v1);
    int far0 = (int)((u0 ^ u1) & (NPTS - 1));
    int far1 = (int)((v0 ^ v1) & (NPTS - 1));

    hipLaunchKernelGGL(fps_kernel, dim3(1), dim3(TFPS), 0, stream,
                       xyz, new_xyz, far0, far1);
    hipLaunchKernelGGL(group_mlp_kernel, dim3(NB * SOUT / 2), dim3(T2), 0, stream,
                       xyz, points, w1, b1, w2, b2, w3, b3, new_xyz, new_points);
}

// Round 8
// 413.991 us; speedup vs baseline: 1.2940x; 1.2940x over previous
//
#include <hip/hip_runtime.h>
#include <stdint.h>

#define NPTS 2048
#define SOUT 512
#define NB   2
#define TB   256
#define PPT  8             // fps: points per lane, k-major
#define NW   4             // fps: waves per batch
#define FMAGIC 0xC0DE0000u

typedef float vf2 __attribute__((ext_vector_type(2)));

// ---- DPP wave64 max-reduce (nonneg values; bound_ctrl zero-fill is safe) ----
__device__ __forceinline__ float wave_allmax_f32(float v) {
    int x = __float_as_int(v); int t;
    t = __builtin_amdgcn_update_dpp(x, x, 0x111, 0xF, 0xF, true); v = fmaxf(v, __int_as_float(t)); x = __float_as_int(v);
    t = __builtin_amdgcn_update_dpp(x, x, 0x112, 0xF, 0xF, true); v = fmaxf(v, __int_as_float(t)); x = __float_as_int(v);
    t = __builtin_amdgcn_update_dpp(x, x, 0x114, 0xF, 0xF, true); v = fmaxf(v, __int_as_float(t)); x = __float_as_int(v);
    t = __builtin_amdgcn_update_dpp(x, x, 0x118, 0xF, 0xF, true); v = fmaxf(v, __int_as_float(t)); x = __float_as_int(v);
    t = __builtin_amdgcn_update_dpp(x, x, 0x142, 0xA, 0xF, true); v = fmaxf(v, __int_as_float(t)); x = __float_as_int(v);
    t = __builtin_amdgcn_update_dpp(x, x, 0x143, 0xC, 0xF, true); v = fmaxf(v, __int_as_float(t)); x = __float_as_int(v);
    return __int_as_float(__builtin_amdgcn_readlane(x, 63));
}
__device__ __forceinline__ float lane_bcast(float v, int l) {
    return __int_as_float(__builtin_amdgcn_readlane(__float_as_int(v), l));
}

// =================== FPS role (R6 proven body; 4 waves, 1 batch) =============
// k-major 8 pts/lane from global (R7-validated init), packed-f32 distance
// (contract off -> bit-exact), coord-carrying local tree, DPP value max +
// ballot/ctz (lowest lane = lowest index), 4-slot parity merge (tie -> lower
// wave = lower index). Publisher: wave 3 lane 32 pushes centroids to global
// in batches of 16 + agent-release flag (overlap with group waves).
__device__ __forceinline__ void fps_role(const float* __restrict__ xb,
                                         float* __restrict__ ob,
                                         unsigned* flagp, int far,
                                         float4* slot /*2*NW*/, float* scf /*1536*/,
                                         int t) {
    const int lane = t & 63;
    const int wvl  = t >> 6;
    float v24[24];
    {
        const float4* src = (const float4*)(xb + t * PPT * 3);
#pragma unroll
        for (int j = 0; j < 6; ++j) {
            float4 a = src[j];
            v24[j*4+0] = a.x; v24[j*4+1] = a.y; v24[j*4+2] = a.z; v24[j*4+3] = a.w;
        }
    }
    vf2 PX[4], PY[4], PZ[4], DD[4];
#pragma unroll
    for (int j = 0; j < 4; ++j) {
        PX[j].x = v24[(2*j)*3+0]; PX[j].y = v24[(2*j+1)*3+0];
        PY[j].x = v24[(2*j)*3+1]; PY[j].y = v24[(2*j+1)*3+1];
        PZ[j].x = v24[(2*j)*3+2]; PZ[j].y = v24[(2*j+1)*3+2];
        DD[j].x = 1e10f; DD[j].y = 1e10f;
    }
    float cx = xb[far*3+0], cy = xb[far*3+1], cz = xb[far*3+2];

    for (int s = 0; s < SOUT; ++s) {
        if (t == 0) { scf[s*3+0] = cx; scf[s*3+1] = cy; scf[s*3+2] = cz; }
        if (s == SOUT - 1) break;
        {
#pragma clang fp contract(off)
            vf2 vcx; vcx.x = cx; vcx.y = cx;
            vf2 vcy; vcy.x = cy; vcy.y = cy;
            vf2 vcz; vcz.x = cz; vcz.y = cz;
#pragma unroll
            for (int j = 0; j < 4; ++j) {
                vf2 dx = PX[j] - vcx;
                vf2 dy = PY[j] - vcy;
                vf2 dz = PZ[j] - vcz;
                vf2 d2 = (dx*dx + dy*dy) + dz*dz;   // ((xx+yy)+zz), rn each
                DD[j].x = fminf(DD[j].x, d2.x);
                DD[j].y = fminf(DD[j].y, d2.y);
            }
        }
        // local argmax, coords carried; left-if->= == first-occurrence
        float v1[4], x1v[4], y1v[4], z1v[4];
#pragma unroll
        for (int j = 0; j < 4; ++j) {
            bool l = DD[j].x >= DD[j].y;
            v1[j]  = l ? DD[j].x : DD[j].y;
            x1v[j] = l ? PX[j].x : PX[j].y;
            y1v[j] = l ? PY[j].x : PY[j].y;
            z1v[j] = l ? PZ[j].x : PZ[j].y;
        }
        float v2v[2], x2v[2], y2v[2], z2v[2];
#pragma unroll
        for (int j = 0; j < 2; ++j) {
            bool l = v1[2*j] >= v1[2*j+1];
            v2v[j] = l ? v1[2*j]  : v1[2*j+1];
            x2v[j] = l ? x1v[2*j] : x1v[2*j+1];
            y2v[j] = l ? y1v[2*j] : y1v[2*j+1];
            z2v[j] = l ? z1v[2*j] : z1v[2*j+1];
        }
        bool lf = v2v[0] >= v2v[1];
        float bv = lf ? v2v[0] : v2v[1];
        float bx = lf ? x2v[0] : x2v[1];
        float by = lf ? y2v[0] : y2v[1];
        float bz = lf ? z2v[0] : z2v[1];
        float wmax = wave_allmax_f32(bv);
        unsigned long long msk = __ballot(bv == wmax);
        int l0 = (int)__builtin_ctzll(msk);
        float wx = lane_bcast(bx, l0);
        float wy = lane_bcast(by, l0);
        float wz = lane_bcast(bz, l0);
        const int par = s & 1;
        if (lane == 0) slot[par*NW + wvl] = make_float4(wmax, wx, wy, wz);
        __syncthreads();
        float4 a0 = slot[par*NW + 0];
        float bvv = a0.x; cx = a0.y; cy = a0.z; cz = a0.w;
#pragma unroll
        for (int w = 1; w < NW; ++w) {
            float4 aw = slot[par*NW + w];
            bool take = aw.x > bvv;            // tie -> lower wave = lower idx
            bvv = take ? aw.x : bvv;
            cx  = take ? aw.y : cx;
            cy  = take ? aw.z : cy;
            cz  = take ? aw.w : cz;
        }
        // publisher: every 16 rounds push scf[s-16..s) to global + flag
        if (flagp && wvl == 3 && lane == 32 && s >= 16 && (s & 15) == 0) {
            const int base = s - 16;               // multiple of 16 -> 16B aligned
            const float4* ss = (const float4*)(scf + base*3);
            float4* dd4 = (float4*)(ob + base*3);
#pragma unroll
            for (int j = 0; j < 12; ++j) dd4[j] = ss[j];
            __threadfence();                       // agent release of the stores
            __hip_atomic_store(flagp, FMAGIC + (unsigned)s,
                               __ATOMIC_RELEASE, __HIP_MEMORY_SCOPE_AGENT);
        }
    }
    __syncthreads();                               // scf[511] visible
    if (flagp) {
        if (wvl == 3 && lane == 32) {
            const float4* ss = (const float4*)(scf + 496*3);
            float4* dd4 = (float4*)(ob + 496*3);
#pragma unroll
            for (int j = 0; j < 12; ++j) dd4[j] = ss[j];
            __threadfence();
            __hip_atomic_store(flagp, FMAGIC + 512u,
                               __ATOMIC_RELEASE, __HIP_MEMORY_SCOPE_AGENT);
        }
    } else {
        for (int i = t; i < SOUT * 3; i += TB) ob[i] = scf[i];
    }
}

// =================== group role (R6 proven body; 1 wave, 1 query) ============
__device__ __forceinline__ void group_role(
        const float* __restrict__ xyz,  const float* __restrict__ points,
        const float* __restrict__ w1,   const float* __restrict__ b1,
        const float* __restrict__ w2,   const float* __restrict__ b2,
        const float* __restrict__ w3,   const float* __restrict__ b3,
        const float* __restrict__ new_xyz, float* __restrict__ new_points,
        const unsigned* flags, unsigned short* sidx, float* sh2,
        int lane, int q) {
    float wf3[32];
    {
        const float4* w3v = (const float4*)(w3 + lane * 32);
#pragma unroll
        for (int j = 0; j < 8; ++j) {
            float4 v = w3v[j];
            wf3[j*4+0] = v.x; wf3[j*4+1] = v.y; wf3[j*4+2] = v.z; wf3[j*4+3] = v.w;
        }
    }
    const float rb3 = b3[lane];
    const int b = q >> 9;
    const int s = q & (SOUT - 1);

    if (flags) {
        const unsigned* flagp = flags + (b << 6);   // 256 B apart
        if (lane == 0) {
            const unsigned tgt = FMAGIC + (unsigned)s + 1u;
            int polls = 0;
            for (;;) {
                unsigned v = __hip_atomic_load(flagp, __ATOMIC_ACQUIRE,
                                               __HIP_MEMORY_SCOPE_AGENT);
                if (v >= tgt && v <= FMAGIC + 512u) break;
                if (++polls > (1 << 18)) break;     // hang insurance
                __builtin_amdgcn_s_sleep(32);
            }
        }
        __threadfence();                            // wave-wide acquire
    }
    // coords via agent-scope loads (coherent across XCDs)
    const unsigned* nx = (const unsigned*)new_xyz + (size_t)q * 3;
    const float qx = __uint_as_float(__hip_atomic_load(nx + 0, __ATOMIC_RELAXED, __HIP_MEMORY_SCOPE_AGENT));
    const float qy = __uint_as_float(__hip_atomic_load(nx + 1, __ATOMIC_RELAXED, __HIP_MEMORY_SCOPE_AGENT));
    const float qz = __uint_as_float(__hip_atomic_load(nx + 2, __ATOMIC_RELAXED, __HIP_MEMORY_SCOPE_AGENT));
    const float qs = __fadd_rn(__fadd_rn(__fmul_rn(qx,qx), __fmul_rn(qy,qy)), __fmul_rn(qz,qz));
    const float* xb = xyz    + (size_t)b * NPTS * 3;
    const float* pb = points + (size_t)b * 13 * NPTS;

    // scan all N points, ballot-compact within-radius indices (ascending)
    int cnt = 0;
    const unsigned long long lm = (1ull << lane) - 1ull;
    for (int r = 0; r < NPTS / 64; ++r) {
        int n = r * 64 + lane;
        float x = xb[n*3+0], y = xb[n*3+1], z = xb[n*3+2];
        float pn = __fadd_rn(__fadd_rn(__fmul_rn(x,x), __fmul_rn(y,y)), __fmul_rn(z,z));
        float dt = __fadd_rn(__fadd_rn(__fmul_rn(qx,x), __fmul_rn(qy,y)), __fmul_rn(qz,z));
        float sqr = __fsub_rn(__fadd_rn(qs, pn), __fmul_rn(2.0f, dt));
        bool sel = !(sqr > 0.04f);                 // keep iff sqr <= r^2 (f32)
        unsigned long long m = __ballot(sel);
        if (sel) sidx[cnt + __popcll(m & lm)] = (unsigned short)n;
        cnt += (int)__popcll(m);
    }
    const int K = cnt;                             // >= 1
    const int nfirst = (int)sidx[0];

    float mx = -3.0e38f;
    for (int tb = 0; tb < K; tb += 64) {
        int m = tb + lane;
        int n = (m < K) ? (int)sidx[m] : nfirst;   // pad = first neighbor
        float f[16];
        f[0] = xb[n*3+0] - qx;
        f[1] = xb[n*3+1] - qy;
        f[2] = xb[n*3+2] - qz;
#pragma unroll
        for (int c = 0; c < 13; ++c) f[3+c] = pb[c*NPTS + n];
        float h1[32];
#pragma unroll
        for (int o = 0; o < 32; ++o) {
            float acc = b1[o];                     // uniform -> s_load
            const float4* wr = (const float4*)(w1 + o*16);
#pragma unroll
            for (int c4 = 0; c4 < 4; ++c4) {
                float4 wv = wr[c4];
                acc = fmaf(f[c4*4+0], wv.x, acc);
                acc = fmaf(f[c4*4+1], wv.y, acc);
                acc = fmaf(f[c4*4+2], wv.z, acc);
                acc = fmaf(f[c4*4+3], wv.w, acc);
            }
            h1[o] = fmaxf(acc, 0.0f);
        }
        float h2[32];
#pragma unroll
        for (int o = 0; o < 32; ++o) {
            float acc = b2[o];                     // uniform -> s_load
            const float4* wr = (const float4*)(w2 + o*32);
#pragma unroll
            for (int c4 = 0; c4 < 8; ++c4) {
                float4 wv = wr[c4];
                acc = fmaf(h1[c4*4+0], wv.x, acc);
                acc = fmaf(h1[c4*4+1], wv.y, acc);
                acc = fmaf(h1[c4*4+2], wv.z, acc);
                acc = fmaf(h1[c4*4+3], wv.w, acc);
            }
            h2[o] = fmaxf(acc, 0.0f);
        }
        {
            float4* row = (float4*)(sh2 + lane * 36);
#pragma unroll
            for (int c4 = 0; c4 < 8; ++c4)
                row[c4] = make_float4(h2[c4*4+0], h2[c4*4+1], h2[c4*4+2], h2[c4*4+3]);
        }
        int rows = K - tb; if (rows > 64) rows = 64;
#pragma unroll 4
        for (int n2 = 0; n2 < rows; ++n2) {
            const float4* hr = (const float4*)(sh2 + n2 * 36);
            float acc = rb3;
#pragma unroll
            for (int c4 = 0; c4 < 8; ++c4) {
                float4 h = hr[c4];
                acc = fmaf(h.x, wf3[c4*4+0], acc);
                acc = fmaf(h.y, wf3[c4*4+1], acc);
                acc = fmaf(h.z, wf3[c4*4+2], acc);
                acc = fmaf(h.w, wf3[c4*4+3], acc);
            }
            mx = fmaxf(mx, acc);
        }
        // single wave: DS ops in-order -> no barrier between chunks
    }
    new_points[((size_t)b * 64 + lane) * SOUT + s] = mx;   // (B, 64, S)
}

// =================== fused kernel: blocks 0-1 fps, 2-257 group ===============
__global__ __launch_bounds__(TB, 1) void fused_kernel(
        const float* __restrict__ xyz,  const float* __restrict__ points,
        const float* __restrict__ w1,   const float* __restrict__ b1,
        const float* __restrict__ w2,   const float* __restrict__ b2,
        const float* __restrict__ w3,   const float* __restrict__ b3,
        float* __restrict__ new_xyz, float* __restrict__ new_points,
        unsigned* flags, int far0, int far1) {
    __shared__ float4 s_slot[2 * NW];
    __shared__ __align__(16) float s_scf[SOUT * 3];
    __shared__ unsigned short s_sidx[4 * NPTS];
    __shared__ __align__(16) float s_sh2[4 * 64 * 36];
    const int blk = blockIdx.x;
    const int tid = threadIdx.x;
    if (blk < 2) {
        const int bg = blk;
        fps_role(xyz + (size_t)bg * NPTS * 3,
                 new_xyz + (size_t)bg * SOUT * 3,
                 flags + (bg << 6),
                 (bg == 0) ? far0 : far1,
                 s_slot, s_scf, tid);
    } else {
        const int lane = tid & 63;
        const int wvl  = tid >> 6;
        const int q    = (blk - 2) * 4 + wvl;     // 1024 queries
        group_role(xyz, points, w1, b1, w2, b2, w3, b3, new_xyz, new_points,
                   flags, s_sidx + wvl * NPTS, s_sh2 + wvl * 64 * 36, lane, q);
    }
}

// =================== fallback kernels (ws too small): serial R6 path =========
__global__ __launch_bounds__(TB, 1) void fps_kernel(const float* __restrict__ xyz,
                                                    float* __restrict__ new_xyz,
                                                    int far0, int far1) {
    __shared__ float4 s_slot[2 * NW];
    __shared__ __align__(16) float s_scf[SOUT * 3];
    const int bg = blockIdx.x;
    fps_role(xyz + (size_t)bg * NPTS * 3, new_xyz + (size_t)bg * SOUT * 3,
             nullptr, (bg == 0) ? far0 : far1, s_slot, s_scf, threadIdx.x);
}
__global__ __launch_bounds__(64, 1) void group_kernel(
        const float* __restrict__ xyz,  const float* __restrict__ points,
        const float* __restrict__ w1,   const float* __restrict__ b1,
        const float* __restrict__ w2,   const float* __restrict__ b2,
        const float* __restrict__ w3,   const float* __restrict__ b3,
        const float* __restrict__ new_xyz, float* __restrict__ new_points) {
    __shared__ unsigned short s_sidx[NPTS];
    __shared__ __align__(16) float s_sh2[64 * 36];
    group_role(xyz, points, w1, b1, w2, b2, w3, b3, new_xyz, new_points,
               nullptr, s_sidx, s_sh2, threadIdx.x, blockIdx.x);
}

// ---------------- host: threefry2x32 (JAX key(42) randint seed) --------------
static inline uint32_t rotl32(uint32_t x, int r) { return (x << r) | (x >> (32 - r)); }
static void threefry2x32_host(uint32_t k0, uint32_t k1, uint32_t& x0, uint32_t& x1) {
    const int R[2][4] = {{13,15,26,6},{17,29,16,24}};
    uint32_t ks[3] = {k0, k1, k0 ^ k1 ^ 0x1BD11BDAu};
    x0 += ks[0]; x1 += ks[1];
    for (int i = 0; i < 5; ++i) {
        for (int j = 0; j < 4; ++j) { x0 += x1; x1 = rotl32(x1, R[i & 1][j]); x1 ^= x0; }
        x0 += ks[(i + 1) % 3];
        x1 += ks[(i + 2) % 3] + (uint32_t)(i + 1);
    }
}

extern "C" void kernel_launch(void* const* d_in, const int* in_sizes, int n_in,
                              void* d_out, int out_size, void* d_ws, size_t ws_size,
                              hipStream_t stream) {
    const float* xyz    = (const float*)d_in[0];
    const float* points = (const float*)d_in[1];
    const float* w1 = (const float*)d_in[2];
    const float* b1 = (const float*)d_in[3];
    const float* w2 = (const float*)d_in[4];
    const float* b2 = (const float*)d_in[5];
    const float* w3 = (const float*)d_in[6];
    const float* b3 = (const float*)d_in[7];
    float* out        = (float*)d_out;
    float* new_xyz    = out;                      // (B, S, 3)
    float* new_points = out + NB * SOUT * 3;      // (B, 64, S)

    // jax.random.randint(key(42), (2,), 0, 2048), modern JAX
    // (jax_threefry_partitionable=True): _randint splits the key first:
    //   k1, k2 = split(key); result = random_bits(k2, 32, (2,)) & 2047
    // foldlike split: k2 = threefry((0,42),(0,1)) full pair.
    // partitionable bits: elem i = xor-halves of threefry(k2, (0,i)).
    // (VERIFIED passing in rounds 3-7 — do not change.)
    uint32_t k2a = 0, k2b = 1; threefry2x32_host(0u, 42u, k2a, k2b);
    uint32_t u0 = 0, u1 = 0;  threefry2x32_host(k2a, k2b, u0, u1);
    uint32_t v0 = 0, v1 = 1;  threefry2x32_host(k2a, k2b, v0, v1);
    int far0 = (int)((u0 ^ u1) & (NPTS - 1));
    int far1 = (int)((v0 ^ v1) & (NPTS - 1));

    if (ws_size >= 512) {
        // fused producer-consumer: flags live in d_ws (poison 0xAAAAAAAA < FMAGIC
        // -> consumers spin until this launch's publisher writes).
        hipLaunchKernelGGL(fused_kernel, dim3(2 + NB * SOUT / 4), dim3(TB), 0, stream,
                           xyz, points, w1, b1, w2, b2, w3, b3,
                           new_xyz, new_points, (unsigned*)d_ws, far0, far1);
    } else {
        hipLaunchKernelGGL(fps_kernel, dim3(NB), dim3(TB), 0, stream,
                           xyz, new_xyz, far0, far1);
        hipLaunchKernelGGL(group_kernel, dim3(NB * SOUT), dim3(64), 0, stream,
                           xyz, points, w1, b1, w2, b2, w3, b3, new_xyz, new_points);
    }
}

// Round 9
// 367.094 us; speedup vs baseline: 1.4593x; 1.1278x over previous
//
#include <hip/hip_runtime.h>
#include <stdint.h>

#define NPTS 2048
#define SOUT 512
#define NB   2
#define TB   256
#define PPT  8             // fps: points per lane, k-major
#define NW   4             // fps: waves per batch
#define FMAGIC 0xC0DE0000u

typedef float vf2 __attribute__((ext_vector_type(2)));

// ---- DPP wave64 max-reduce (nonneg values; bound_ctrl zero-fill is safe) ----
__device__ __forceinline__ float wave_allmax_f32(float v) {
    int x = __float_as_int(v); int t;
    t = __builtin_amdgcn_update_dpp(x, x, 0x111, 0xF, 0xF, true); v = fmaxf(v, __int_as_float(t)); x = __float_as_int(v);
    t = __builtin_amdgcn_update_dpp(x, x, 0x112, 0xF, 0xF, true); v = fmaxf(v, __int_as_float(t)); x = __float_as_int(v);
    t = __builtin_amdgcn_update_dpp(x, x, 0x114, 0xF, 0xF, true); v = fmaxf(v, __int_as_float(t)); x = __float_as_int(v);
    t = __builtin_amdgcn_update_dpp(x, x, 0x118, 0xF, 0xF, true); v = fmaxf(v, __int_as_float(t)); x = __float_as_int(v);
    t = __builtin_amdgcn_update_dpp(x, x, 0x142, 0xA, 0xF, true); v = fmaxf(v, __int_as_float(t)); x = __float_as_int(v);
    t = __builtin_amdgcn_update_dpp(x, x, 0x143, 0xC, 0xF, true); v = fmaxf(v, __int_as_float(t)); x = __float_as_int(v);
    return __int_as_float(__builtin_amdgcn_readlane(x, 63));
}
__device__ __forceinline__ float lane_bcast(float v, int l) {
    return __int_as_float(__builtin_amdgcn_readlane(__float_as_int(v), l));
}

// =================== FPS role (R6 proven math; 4 waves, 1 batch) =============
// FUSED mode: publisher (wave 3 lane 32) fire-and-forget agent-relaxed coord
// stores every round; release-flag every 16 rounds placed BEFORE that round's
// store so its vmcnt(0) is naturally drained; raw s_barrier + lgkm-only wait
// keeps in-flight stores out of the round-critical path.
template<bool FUSED>
__device__ __forceinline__ void fps_role(const float* __restrict__ xb,
                                         float* __restrict__ ob,
                                         unsigned* flagp, int far,
                                         float4* slot /*2*NW*/, float* scf,
                                         int t) {
    const int lane = t & 63;
    const int wvl  = t >> 6;
    float v24[24];
    {
        const float4* src = (const float4*)(xb + t * PPT * 3);
#pragma unroll
        for (int j = 0; j < 6; ++j) {
            float4 a = src[j];
            v24[j*4+0] = a.x; v24[j*4+1] = a.y; v24[j*4+2] = a.z; v24[j*4+3] = a.w;
        }
    }
    vf2 PX[4], PY[4], PZ[4], DD[4];
#pragma unroll
    for (int j = 0; j < 4; ++j) {
        PX[j].x = v24[(2*j)*3+0]; PX[j].y = v24[(2*j+1)*3+0];
        PY[j].x = v24[(2*j)*3+1]; PY[j].y = v24[(2*j+1)*3+1];
        PZ[j].x = v24[(2*j)*3+2]; PZ[j].y = v24[(2*j+1)*3+2];
        DD[j].x = 1e10f; DD[j].y = 1e10f;
    }
    float cx = xb[far*3+0], cy = xb[far*3+1], cz = xb[far*3+2];

    for (int s = 0; s < SOUT; ++s) {
        if (FUSED) {
            if (wvl == 3 && lane == 32) {
                if (s >= 16 && (s & 15) == 0)   // covers centroids < s; prior
                    __hip_atomic_store(flagp, FMAGIC + (unsigned)s,   // stores drained
                                       __ATOMIC_RELEASE, __HIP_MEMORY_SCOPE_AGENT);
                unsigned* o = (unsigned*)ob + s * 3;
                __hip_atomic_store(o + 0, __float_as_uint(cx), __ATOMIC_RELAXED, __HIP_MEMORY_SCOPE_AGENT);
                __hip_atomic_store(o + 1, __float_as_uint(cy), __ATOMIC_RELAXED, __HIP_MEMORY_SCOPE_AGENT);
                __hip_atomic_store(o + 2, __float_as_uint(cz), __ATOMIC_RELAXED, __HIP_MEMORY_SCOPE_AGENT);
            }
        } else {
            if (t == 0) { scf[s*3+0] = cx; scf[s*3+1] = cy; scf[s*3+2] = cz; }
        }
        if (s == SOUT - 1) break;
        {
#pragma clang fp contract(off)
            vf2 vcx; vcx.x = cx; vcx.y = cx;
            vf2 vcy; vcy.x = cy; vcy.y = cy;
            vf2 vcz; vcz.x = cz; vcz.y = cz;
#pragma unroll
            for (int j = 0; j < 4; ++j) {
                vf2 dx = PX[j] - vcx;
                vf2 dy = PY[j] - vcy;
                vf2 dz = PZ[j] - vcz;
                vf2 d2 = (dx*dx + dy*dy) + dz*dz;   // ((xx+yy)+zz), rn each
                DD[j].x = fminf(DD[j].x, d2.x);
                DD[j].y = fminf(DD[j].y, d2.y);
            }
        }
        // local argmax, coords carried; left-if->= == first-occurrence
        float v1[4], x1v[4], y1v[4], z1v[4];
#pragma unroll
        for (int j = 0; j < 4; ++j) {
            bool l = DD[j].x >= DD[j].y;
            v1[j]  = l ? DD[j].x : DD[j].y;
            x1v[j] = l ? PX[j].x : PX[j].y;
            y1v[j] = l ? PY[j].x : PY[j].y;
            z1v[j] = l ? PZ[j].x : PZ[j].y;
        }
        float v2v[2], x2v[2], y2v[2], z2v[2];
#pragma unroll
        for (int j = 0; j < 2; ++j) {
            bool l = v1[2*j] >= v1[2*j+1];
            v2v[j] = l ? v1[2*j]  : v1[2*j+1];
            x2v[j] = l ? x1v[2*j] : x1v[2*j+1];
            y2v[j] = l ? y1v[2*j] : y1v[2*j+1];
            z2v[j] = l ? z1v[2*j] : z1v[2*j+1];
        }
        bool lf = v2v[0] >= v2v[1];
        float bv = lf ? v2v[0] : v2v[1];
        float bx = lf ? x2v[0] : x2v[1];
        float by = lf ? y2v[0] : y2v[1];
        float bz = lf ? z2v[0] : z2v[1];
        float wmax = wave_allmax_f32(bv);
        unsigned long long msk = __ballot(bv == wmax);
        int l0 = (int)__builtin_ctzll(msk);
        float wx = lane_bcast(bx, l0);
        float wy = lane_bcast(by, l0);
        float wz = lane_bcast(bz, l0);
        const int par = s & 1;
        if (lane == 0) slot[par*NW + wvl] = make_float4(wmax, wx, wy, wz);
        if (FUSED) {
            // lgkm-only drain (slot handoff) -> publisher vmem stays in flight
            __builtin_amdgcn_s_waitcnt(0xC07F);   // vmcnt(63) exp(7) lgkmcnt(0)
            __builtin_amdgcn_s_barrier();
        } else {
            __syncthreads();
        }
        float4 a0 = slot[par*NW + 0];
        float bvv = a0.x; cx = a0.y; cy = a0.z; cz = a0.w;
#pragma unroll
        for (int w = 1; w < NW; ++w) {
            float4 aw = slot[par*NW + w];
            bool take = aw.x > bvv;            // tie -> lower wave = lower idx
            bvv = take ? aw.x : bvv;
            cx  = take ? aw.y : cx;
            cy  = take ? aw.z : cy;
            cz  = take ? aw.w : cz;
        }
    }
    if (FUSED) {
        if (wvl == 3 && lane == 32)            // covers centroid 511 (stored above)
            __hip_atomic_store(flagp, FMAGIC + 512u,
                               __ATOMIC_RELEASE, __HIP_MEMORY_SCOPE_AGENT);
    } else {
        __syncthreads();
        for (int i = t; i < SOUT * 3; i += TB) ob[i] = scf[i];
    }
}

// =================== group role (R6/R8 proven body; 1 wave, 1 query) =========
__device__ __forceinline__ void group_role(
        const float* __restrict__ xyz,  const float* __restrict__ points,
        const float* __restrict__ w1,   const float* __restrict__ b1,
        const float* __restrict__ w2,   const float* __restrict__ b2,
        const float* __restrict__ w3,   const float* __restrict__ b3,
        const float* __restrict__ new_xyz, float* __restrict__ new_points,
        const unsigned* flags, unsigned short* sidx, float* sh2,
        int lane, int q) {
    float wf3[32];
    {
        const float4* w3v = (const float4*)(w3 + lane * 32);
#pragma unroll
        for (int j = 0; j < 8; ++j) {
            float4 v = w3v[j];
            wf3[j*4+0] = v.x; wf3[j*4+1] = v.y; wf3[j*4+2] = v.z; wf3[j*4+3] = v.w;
        }
    }
    const float rb3 = b3[lane];
    const int b = q >> 9;
    const int s = q & (SOUT - 1);

    if (flags) {
        const unsigned* flagp = flags + (b << 6);   // 256 B apart
        if (lane == 0) {
            const unsigned tgt = FMAGIC + (unsigned)s + 1u;
            int polls = 0;
            for (;;) {
                unsigned v = __hip_atomic_load(flagp, __ATOMIC_ACQUIRE,
                                               __HIP_MEMORY_SCOPE_AGENT);
                if (v >= tgt && v <= FMAGIC + 512u) break;
                if (++polls > (1 << 18)) break;     // hang insurance
                __builtin_amdgcn_s_sleep(32);
            }
        }
        __threadfence();                            // wave-wide acquire
    }
    const unsigned* nx = (const unsigned*)new_xyz + (size_t)q * 3;
    const float qx = __uint_as_float(__hip_atomic_load(nx + 0, __ATOMIC_RELAXED, __HIP_MEMORY_SCOPE_AGENT));
    const float qy = __uint_as_float(__hip_atomic_load(nx + 1, __ATOMIC_RELAXED, __HIP_MEMORY_SCOPE_AGENT));
    const float qz = __uint_as_float(__hip_atomic_load(nx + 2, __ATOMIC_RELAXED, __HIP_MEMORY_SCOPE_AGENT));
    const float qs = __fadd_rn(__fadd_rn(__fmul_rn(qx,qx), __fmul_rn(qy,qy)), __fmul_rn(qz,qz));
    const float* xb = xyz    + (size_t)b * NPTS * 3;
    const float* pb = points + (size_t)b * 13 * NPTS;

    int cnt = 0;
    const unsigned long long lm = (1ull << lane) - 1ull;
    for (int r = 0; r < NPTS / 64; ++r) {
        int n = r * 64 + lane;
        float x = xb[n*3+0], y = xb[n*3+1], z = xb[n*3+2];
        float pn = __fadd_rn(__fadd_rn(__fmul_rn(x,x), __fmul_rn(y,y)), __fmul_rn(z,z));
        float dt = __fadd_rn(__fadd_rn(__fmul_rn(qx,x), __fmul_rn(qy,y)), __fmul_rn(qz,z));
        float sqr = __fsub_rn(__fadd_rn(qs, pn), __fmul_rn(2.0f, dt));
        bool sel = !(sqr > 0.04f);                 // keep iff sqr <= r^2 (f32)
        unsigned long long m = __ballot(sel);
        if (sel) sidx[cnt + __popcll(m & lm)] = (unsigned short)n;
        cnt += (int)__popcll(m);
    }
    const int K = cnt;                             // >= 1
    const int nfirst = (int)sidx[0];

    float mx = -3.0e38f;
    for (int tb = 0; tb < K; tb += 64) {
        int m = tb + lane;
        int n = (m < K) ? (int)sidx[m] : nfirst;   // pad = first neighbor
        float f[16];
        f[0] = xb[n*3+0] - qx;
        f[1] = xb[n*3+1] - qy;
        f[2] = xb[n*3+2] - qz;
#pragma unroll
        for (int c = 0; c < 13; ++c) f[3+c] = pb[c*NPTS + n];
        float h1[32];
#pragma unroll
        for (int o = 0; o < 32; ++o) {
            float acc = b1[o];                     // uniform -> s_load
            const float4* wr = (const float4*)(w1 + o*16);
#pragma unroll
            for (int c4 = 0; c4 < 4; ++c4) {
                float4 wv = wr[c4];
                acc = fmaf(f[c4*4+0], wv.x, acc);
                acc = fmaf(f[c4*4+1], wv.y, acc);
                acc = fmaf(f[c4*4+2], wv.z, acc);
                acc = fmaf(f[c4*4+3], wv.w, acc);
            }
            h1[o] = fmaxf(acc, 0.0f);
        }
        float h2[32];
#pragma unroll
        for (int o = 0; o < 32; ++o) {
            float acc = b2[o];                     // uniform -> s_load
            const float4* wr = (const float4*)(w2 + o*32);
#pragma unroll
            for (int c4 = 0; c4 < 8; ++c4) {
                float4 wv = wr[c4];
                acc = fmaf(h1[c4*4+0], wv.x, acc);
                acc = fmaf(h1[c4*4+1], wv.y, acc);
                acc = fmaf(h1[c4*4+2], wv.z, acc);
                acc = fmaf(h1[c4*4+3], wv.w, acc);
            }
            h2[o] = fmaxf(acc, 0.0f);
        }
        {
            float4* row = (float4*)(sh2 + lane * 36);
#pragma unroll
            for (int c4 = 0; c4 < 8; ++c4)
                row[c4] = make_float4(h2[c4*4+0], h2[c4*4+1], h2[c4*4+2], h2[c4*4+3]);
        }
        int rows = K - tb; if (rows > 64) rows = 64;
#pragma unroll 4
        for (int n2 = 0; n2 < rows; ++n2) {
            const float4* hr = (const float4*)(sh2 + n2 * 36);
            float acc = rb3;
#pragma unroll
            for (int c4 = 0; c4 < 8; ++c4) {
                float4 h = hr[c4];
                acc = fmaf(h.x, wf3[c4*4+0], acc);
                acc = fmaf(h.y, wf3[c4*4+1], acc);
                acc = fmaf(h.z, wf3[c4*4+2], acc);
                acc = fmaf(h.w, wf3[c4*4+3], acc);
            }
            mx = fmaxf(mx, acc);
        }
        // single wave: DS ops in-order -> no barrier between chunks
    }
    new_points[((size_t)b * 64 + lane) * SOUT + s] = mx;   // (B, 64, S)
}

// =================== fused kernel: blocks 0-1 fps, 2-257 group ===============
__global__ __launch_bounds__(TB, 1) void fused_kernel(
        const float* __restrict__ xyz,  const float* __restrict__ points,
        const float* __restrict__ w1,   const float* __restrict__ b1,
        const float* __restrict__ w2,   const float* __restrict__ b2,
        const float* __restrict__ w3,   const float* __restrict__ b3,
        float* __restrict__ new_xyz, float* __restrict__ new_points,
        unsigned* flags, int far0, int far1) {
    __shared__ float4 s_slot[2 * NW];
    __shared__ unsigned short s_sidx[4 * NPTS];
    __shared__ __align__(16) float s_sh2[4 * 64 * 36];
    const int blk = blockIdx.x;
    const int tid = threadIdx.x;
    if (blk < 2) {
        const int bg = blk;
        fps_role<true>(xyz + (size_t)bg * NPTS * 3,
                       new_xyz + (size_t)bg * SOUT * 3,
                       flags + (bg << 6),
                       (bg == 0) ? far0 : far1,
                       s_slot, nullptr, tid);
    } else {
        const int lane = tid & 63;
        const int wvl  = tid >> 6;
        const int q    = (blk - 2) * 4 + wvl;     // 1024 queries
        group_role(xyz, points, w1, b1, w2, b2, w3, b3, new_xyz, new_points,
                   flags, s_sidx + wvl * NPTS, s_sh2 + wvl * 64 * 36, lane, q);
    }
}

// =================== fallback kernels (ws too small): serial R6 path =========
__global__ __launch_bounds__(TB, 1) void fps_kernel(const float* __restrict__ xyz,
                                                    float* __restrict__ new_xyz,
                                                    int far0, int far1) {
    __shared__ float4 s_slot[2 * NW];
    __shared__ __align__(16) float s_scf[SOUT * 3];
    const int bg = blockIdx.x;
    fps_role<false>(xyz + (size_t)bg * NPTS * 3, new_xyz + (size_t)bg * SOUT * 3,
                    nullptr, (bg == 0) ? far0 : far1, s_slot, s_scf, threadIdx.x);
}
__global__ __launch_bounds__(64, 1) void group_kernel(
        const float* __restrict__ xyz,  const float* __restrict__ points,
        const float* __restrict__ w1,   const float* __restrict__ b1,
        const float* __restrict__ w2,   const float* __restrict__ b2,
        const float* __restrict__ w3,   const float* __restrict__ b3,
        const float* __restrict__ new_xyz, float* __restrict__ new_points) {
    __shared__ unsigned short s_sidx[NPTS];
    __shared__ __align__(16) float s_sh2[64 * 36];
    group_role(xyz, points, w1, b1, w2, b2, w3, b3, new_xyz, new_points,
               nullptr, s_sidx, s_sh2, threadIdx.x, blockIdx.x);
}

// ---------------- host: threefry2x32 (JAX key(42) randint seed) --------------
static inline uint32_t rotl32(uint32_t x, int r) { return (x << r) | (x >> (32 - r)); }
static void threefry2x32_host(uint32_t k0, uint32_t k1, uint32_t& x0, uint32_t& x1) {
    const int R[2][4] = {{13,15,26,6},{17,29,16,24}};
    uint32_t ks[3] = {k0, k1, k0 ^ k1 ^ 0x1BD11BDAu};
    x0 += ks[0]; x1 += ks[1];
    for (int i = 0; i < 5; ++i) {
        for (int j = 0; j < 4; ++j) { x0 += x1; x1 = rotl32(x1, R[i & 1][j]); x1 ^= x0; }
        x0 += ks[(i + 1) % 3];
        x1 += ks[(i + 2) % 3] + (uint32_t)(i + 1);
    }
}

extern "C" void kernel_launch(void* const* d_in, const int* in_sizes, int n_in,
                              void* d_out, int out_size, void* d_ws, size_t ws_size,
                              hipStream_t stream) {
    const float* xyz    = (const float*)d_in[0];
    const float* points = (const float*)d_in[1];
    const float* w1 = (const float*)d_in[2];
    const float* b1 = (const float*)d_in[3];
    const float* w2 = (const float*)d_in[4];
    const float* b2 = (const float*)d_in[5];
    const float* w3 = (const float*)d_in[6];
    const float* b3 = (const float*)d_in[7];
    float* out        = (float*)d_out;
    float* new_xyz    = out;                      // (B, S, 3)
    float* new_points = out + NB * SOUT * 3;      // (B, 64, S)

    // jax.random.randint(key(42), (2,), 0, 2048), modern JAX
    // (jax_threefry_partitionable=True): _randint splits the key first:
    //   k1, k2 = split(key); result = random_bits(k2, 32, (2,)) & 2047
    // foldlike split: k2 = threefry((0,42),(0,1)) full pair.
    // partitionable bits: elem i = xor-halves of threefry(k2, (0,i)).
    // (VERIFIED passing in rounds 3-8 — do not change.)
    uint32_t k2a = 0, k2b = 1; threefry2x32_host(0u, 42u, k2a, k2b);
    uint32_t u0 = 0, u1 = 0;  threefry2x32_host(k2a, k2b, u0, u1);
    uint32_t v0 = 0, v1 = 1;  threefry2x32_host(k2a, k2b, v0, v1);
    int far0 = (int)((u0 ^ u1) & (NPTS - 1));
    int far1 = (int)((v0 ^ v1) & (NPTS - 1));

    if (ws_size >= 512) {
        // fused producer-consumer: flags in d_ws (poison 0xAAAAAAAA < FMAGIC
        // -> consumers spin until this launch's publisher writes).
        hipLaunchKernelGGL(fused_kernel, dim3(2 + NB * SOUT / 4), dim3(TB), 0, stream,
                           xyz, points, w1, b1, w2, b2, w3, b3,
                           new_xyz, new_points, (unsigned*)d_ws, far0, far1);
    } else {
        hipLaunchKernelGGL(fps_kernel, dim3(NB), dim3(TB), 0, stream,
                           xyz, new_xyz, far0, far1);
        hipLaunchKernelGGL(group_kernel, dim3(NB * SOUT), dim3(64), 0, stream,
                           xyz, points, w1, b1, w2, b2, w3, b3, new_xyz, new_points);
    }
}

// Round 10
// 358.795 us; speedup vs baseline: 1.4931x; 1.0231x over previous
//
#include <hip/hip_runtime.h>
#include <stdint.h>

#define NPTS 2048
#define SOUT 512
#define NB   2
#define TB   256
#define PPT  8             // fps: points per lane, k-major
#define NW   4             // fps: waves per batch
#define FMAGIC 0xC0DE0000u

typedef float vf2 __attribute__((ext_vector_type(2)));

// ---- DPP wave64 max-reduce (nonneg values; bound_ctrl zero-fill is safe) ----
__device__ __forceinline__ float wave_allmax_f32(float v) {
    int x = __float_as_int(v); int t;
    t = __builtin_amdgcn_update_dpp(x, x, 0x111, 0xF, 0xF, true); v = fmaxf(v, __int_as_float(t)); x = __float_as_int(v);
    t = __builtin_amdgcn_update_dpp(x, x, 0x112, 0xF, 0xF, true); v = fmaxf(v, __int_as_float(t)); x = __float_as_int(v);
    t = __builtin_amdgcn_update_dpp(x, x, 0x114, 0xF, 0xF, true); v = fmaxf(v, __int_as_float(t)); x = __float_as_int(v);
    t = __builtin_amdgcn_update_dpp(x, x, 0x118, 0xF, 0xF, true); v = fmaxf(v, __int_as_float(t)); x = __float_as_int(v);
    t = __builtin_amdgcn_update_dpp(x, x, 0x142, 0xA, 0xF, true); v = fmaxf(v, __int_as_float(t)); x = __float_as_int(v);
    t = __builtin_amdgcn_update_dpp(x, x, 0x143, 0xC, 0xF, true); v = fmaxf(v, __int_as_float(t)); x = __float_as_int(v);
    return __int_as_float(__builtin_amdgcn_readlane(x, 63));
}
__device__ __forceinline__ float lane_bcast(float v, int l) {
    return __int_as_float(__builtin_amdgcn_readlane(__float_as_int(v), l));
}
__device__ __forceinline__ float4 sel4(bool c, float4 A, float4 B) {
    float4 r;
    r.x = c ? A.x : B.x; r.y = c ? A.y : B.y;
    r.z = c ? A.z : B.z; r.w = c ? A.w : B.w;
    return r;
}

// =================== FPS role (R6 proven math; 4 waves, 1 batch) =============
// FUSED: tri-lane publisher (wave 3 lanes 32-34, one vmem instr/round, agent-
// relaxed); release flag every 16 rounds BEFORE that round's stores (covers
// rounds < s; wave-wide vmcnt(0) of the release orders all 3 lanes' stores);
// raw s_barrier + lgkm-only waitcnt keeps vmem out of the round-critical path.
template<bool FUSED>
__device__ __forceinline__ void fps_role(const float* __restrict__ xb,
                                         float* __restrict__ ob,
                                         unsigned* flagp, int far,
                                         float4* slot /*2*NW*/, float* scf,
                                         int t) {
    const int lane = t & 63;
    const int wvl  = t >> 6;
    float v24[24];
    {
        const float4* src = (const float4*)(xb + t * PPT * 3);
#pragma unroll
        for (int j = 0; j < 6; ++j) {
            float4 a = src[j];
            v24[j*4+0] = a.x; v24[j*4+1] = a.y; v24[j*4+2] = a.z; v24[j*4+3] = a.w;
        }
    }
    vf2 PX[4], PY[4], PZ[4], DD[4];
#pragma unroll
    for (int j = 0; j < 4; ++j) {
        PX[j].x = v24[(2*j)*3+0]; PX[j].y = v24[(2*j+1)*3+0];
        PY[j].x = v24[(2*j)*3+1]; PY[j].y = v24[(2*j+1)*3+1];
        PZ[j].x = v24[(2*j)*3+2]; PZ[j].y = v24[(2*j+1)*3+2];
        DD[j].x = 1e10f; DD[j].y = 1e10f;
    }
    float cx = xb[far*3+0], cy = xb[far*3+1], cz = xb[far*3+2];

    for (int s = 0; s < SOUT - 1; ++s) {
        if (FUSED) {
            if (wvl == 3) {
                if (lane == 32 && s >= 16 && (s & 15) == 0)   // covers rounds < s
                    __hip_atomic_store(flagp, FMAGIC + (unsigned)s,
                                       __ATOMIC_RELEASE, __HIP_MEMORY_SCOPE_AGENT);
                if (lane >= 32 && lane < 35) {                // one vmem, 3 lanes
                    float v = (lane == 32) ? cx : ((lane == 33) ? cy : cz);
                    unsigned* o = (unsigned*)ob + s * 3 + (lane - 32);
                    __hip_atomic_store(o, __float_as_uint(v),
                                       __ATOMIC_RELAXED, __HIP_MEMORY_SCOPE_AGENT);
                }
            }
        } else {
            if (t == 0) { scf[s*3+0] = cx; scf[s*3+1] = cy; scf[s*3+2] = cz; }
        }
        {
#pragma clang fp contract(off)
            vf2 vcx; vcx.x = cx; vcx.y = cx;
            vf2 vcy; vcy.x = cy; vcy.y = cy;
            vf2 vcz; vcz.x = cz; vcz.y = cz;
#pragma unroll
            for (int j = 0; j < 4; ++j) {
                vf2 dx = PX[j] - vcx;
                vf2 dy = PY[j] - vcy;
                vf2 dz = PZ[j] - vcz;
                vf2 d2 = (dx*dx + dy*dy) + dz*dz;   // ((xx+yy)+zz), rn each
                DD[j].x = fminf(DD[j].x, d2.x);
                DD[j].y = fminf(DD[j].y, d2.y);
            }
        }
        // local argmax, coords carried; left-if->= == first-occurrence
        float v1[4], x1v[4], y1v[4], z1v[4];
#pragma unroll
        for (int j = 0; j < 4; ++j) {
            bool l = DD[j].x >= DD[j].y;
            v1[j]  = l ? DD[j].x : DD[j].y;
            x1v[j] = l ? PX[j].x : PX[j].y;
            y1v[j] = l ? PY[j].x : PY[j].y;
            z1v[j] = l ? PZ[j].x : PZ[j].y;
        }
        float v2v[2], x2v[2], y2v[2], z2v[2];
#pragma unroll
        for (int j = 0; j < 2; ++j) {
            bool l = v1[2*j] >= v1[2*j+1];
            v2v[j] = l ? v1[2*j]  : v1[2*j+1];
            x2v[j] = l ? x1v[2*j] : x1v[2*j+1];
            y2v[j] = l ? y1v[2*j] : y1v[2*j+1];
            z2v[j] = l ? z1v[2*j] : z1v[2*j+1];
        }
        bool lf = v2v[0] >= v2v[1];
        float bv = lf ? v2v[0] : v2v[1];
        float bx = lf ? x2v[0] : x2v[1];
        float by = lf ? y2v[0] : y2v[1];
        float bz = lf ? z2v[0] : z2v[1];
        float wmax = wave_allmax_f32(bv);
        unsigned long long msk = __ballot(bv == wmax);
        int l0 = (int)__builtin_ctzll(msk);
        float wx = lane_bcast(bx, l0);
        float wy = lane_bcast(by, l0);
        float wz = lane_bcast(bz, l0);
        const int par = s & 1;
        if (lane == 0) slot[par*NW + wvl] = make_float4(wmax, wx, wy, wz);
        if (FUSED) {
            // lgkm-only drain (slot handoff) -> publisher vmem stays in flight
            __builtin_amdgcn_s_waitcnt(0xC07F);   // vmcnt(63) exp(7) lgkmcnt(0)
            __builtin_amdgcn_s_barrier();
        } else {
            __syncthreads();
        }
        // depth-2 merge tree; all ties -> lower wave = lower global index
        float4 a0 = slot[par*NW + 0];
        float4 a1 = slot[par*NW + 1];
        float4 a2 = slot[par*NW + 2];
        float4 a3 = slot[par*NW + 3];
        float4 m01 = sel4(a1.x > a0.x, a1, a0);
        float4 m23 = sel4(a3.x > a2.x, a3, a2);
        float4 mf  = sel4(m23.x > m01.x, m23, m01);
        cx = mf.y; cy = mf.z; cz = mf.w;
    }
    // peeled final round: store centroid 511, then final flag
    if (FUSED) {
        if (wvl == 3) {
            if (lane >= 32 && lane < 35) {
                float v = (lane == 32) ? cx : ((lane == 33) ? cy : cz);
                unsigned* o = (unsigned*)ob + (SOUT - 1) * 3 + (lane - 32);
                __hip_atomic_store(o, __float_as_uint(v),
                                   __ATOMIC_RELAXED, __HIP_MEMORY_SCOPE_AGENT);
            }
            if (lane == 32)                    // release: wave-wide vmcnt drain
                __hip_atomic_store(flagp, FMAGIC + 512u,
                                   __ATOMIC_RELEASE, __HIP_MEMORY_SCOPE_AGENT);
        }
    } else {
        if (t == 0) {
            scf[(SOUT-1)*3+0] = cx; scf[(SOUT-1)*3+1] = cy; scf[(SOUT-1)*3+2] = cz;
        }
        __syncthreads();
        for (int i = t; i < SOUT * 3; i += TB) ob[i] = scf[i];
    }
}

// =================== group role (R6/R8 proven body; 1 wave, 1 query) =========
__device__ __forceinline__ void group_role(
        const float* __restrict__ xyz,  const float* __restrict__ points,
        const float* __restrict__ w1,   const float* __restrict__ b1,
        const float* __restrict__ w2,   const float* __restrict__ b2,
        const float* __restrict__ w3,   const float* __restrict__ b3,
        const float* __restrict__ new_xyz, float* __restrict__ new_points,
        const unsigned* flags, unsigned short* sidx, float* sh2,
        int lane, int q) {
    float wf3[32];
    {
        const float4* w3v = (const float4*)(w3 + lane * 32);
#pragma unroll
        for (int j = 0; j < 8; ++j) {
            float4 v = w3v[j];
            wf3[j*4+0] = v.x; wf3[j*4+1] = v.y; wf3[j*4+2] = v.z; wf3[j*4+3] = v.w;
        }
    }
    const float rb3 = b3[lane];
    const int b = q >> 9;
    const int s = q & (SOUT - 1);

    if (flags) {
        const unsigned* flagp = flags + (b << 6);   // 256 B apart
        if (lane == 0) {
            const unsigned tgt = FMAGIC + (unsigned)s + 1u;
            int polls = 0;
            for (;;) {
                unsigned v = __hip_atomic_load(flagp, __ATOMIC_ACQUIRE,
                                               __HIP_MEMORY_SCOPE_AGENT);
                if (v >= tgt && v <= FMAGIC + 512u) break;
                if (++polls > (1 << 18)) break;     // hang insurance
                __builtin_amdgcn_s_sleep(32);
            }
        }
        __threadfence();                            // wave-wide acquire
    }
    const unsigned* nx = (const unsigned*)new_xyz + (size_t)q * 3;
    const float qx = __uint_as_float(__hip_atomic_load(nx + 0, __ATOMIC_RELAXED, __HIP_MEMORY_SCOPE_AGENT));
    const float qy = __uint_as_float(__hip_atomic_load(nx + 1, __ATOMIC_RELAXED, __HIP_MEMORY_SCOPE_AGENT));
    const float qz = __uint_as_float(__hip_atomic_load(nx + 2, __ATOMIC_RELAXED, __HIP_MEMORY_SCOPE_AGENT));
    const float qs = __fadd_rn(__fadd_rn(__fmul_rn(qx,qx), __fmul_rn(qy,qy)), __fmul_rn(qz,qz));
    const float* xb = xyz    + (size_t)b * NPTS * 3;
    const float* pb = points + (size_t)b * 13 * NPTS;

    int cnt = 0;
    const unsigned long long lm = (1ull << lane) - 1ull;
    for (int r = 0; r < NPTS / 64; ++r) {
        int n = r * 64 + lane;
        float x = xb[n*3+0], y = xb[n*3+1], z = xb[n*3+2];
        float pn = __fadd_rn(__fadd_rn(__fmul_rn(x,x), __fmul_rn(y,y)), __fmul_rn(z,z));
        float dt = __fadd_rn(__fadd_rn(__fmul_rn(qx,x), __fmul_rn(qy,y)), __fmul_rn(qz,z));
        float sqr = __fsub_rn(__fadd_rn(qs, pn), __fmul_rn(2.0f, dt));
        bool sel = !(sqr > 0.04f);                 // keep iff sqr <= r^2 (f32)
        unsigned long long m = __ballot(sel);
        if (sel) sidx[cnt + __popcll(m & lm)] = (unsigned short)n;
        cnt += (int)__popcll(m);
    }
    const int K = cnt;                             // >= 1
    const int nfirst = (int)sidx[0];

    float mx = -3.0e38f;
    for (int tb = 0; tb < K; tb += 64) {
        int m = tb + lane;
        int n = (m < K) ? (int)sidx[m] : nfirst;   // pad = first neighbor
        float f[16];
        f[0] = xb[n*3+0] - qx;
        f[1] = xb[n*3+1] - qy;
        f[2] = xb[n*3+2] - qz;
#pragma unroll
        for (int c = 0; c < 13; ++c) f[3+c] = pb[c*NPTS + n];
        float h1[32];
#pragma unroll
        for (int o = 0; o < 32; ++o) {
            float acc = b1[o];                     // uniform -> s_load
            const float4* wr = (const float4*)(w1 + o*16);
#pragma unroll
            for (int c4 = 0; c4 < 4; ++c4) {
                float4 wv = wr[c4];
                acc = fmaf(f[c4*4+0], wv.x, acc);
                acc = fmaf(f[c4*4+1], wv.y, acc);
                acc = fmaf(f[c4*4+2], wv.z, acc);
                acc = fmaf(f[c4*4+3], wv.w, acc);
            }
            h1[o] = fmaxf(acc, 0.0f);
        }
        float h2[32];
#pragma unroll
        for (int o = 0; o < 32; ++o) {
            float acc = b2[o];                     // uniform -> s_load
            const float4* wr = (const float4*)(w2 + o*32);
#pragma unroll
            for (int c4 = 0; c4 < 8; ++c4) {
                float4 wv = wr[c4];
                acc = fmaf(h1[c4*4+0], wv.x, acc);
                acc = fmaf(h1[c4*4+1], wv.y, acc);
                acc = fmaf(h1[c4*4+2], wv.z, acc);
                acc = fmaf(h1[c4*4+3], wv.w, acc);
            }
            h2[o] = fmaxf(acc, 0.0f);
        }
        {
            float4* row = (float4*)(sh2 + lane * 36);
#pragma unroll
            for (int c4 = 0; c4 < 8; ++c4)
                row[c4] = make_float4(h2[c4*4+0], h2[c4*4+1], h2[c4*4+2], h2[c4*4+3]);
        }
        int rows = K - tb; if (rows > 64) rows = 64;
#pragma unroll 4
        for (int n2 = 0; n2 < rows; ++n2) {
            const float4* hr = (const float4*)(sh2 + n2 * 36);
            float acc = rb3;
#pragma unroll
            for (int c4 = 0; c4 < 8; ++c4) {
                float4 h = hr[c4];
                acc = fmaf(h.x, wf3[c4*4+0], acc);
                acc = fmaf(h.y, wf3[c4*4+1], acc);
                acc = fmaf(h.z, wf3[c4*4+2], acc);
                acc = fmaf(h.w, wf3[c4*4+3], acc);
            }
            mx = fmaxf(mx, acc);
        }
        // single wave: DS ops in-order -> no barrier between chunks
    }
    new_points[((size_t)b * 64 + lane) * SOUT + s] = mx;   // (B, 64, S)
}

// =================== fused kernel: blocks 0-1 fps, 2-257 group ===============
__global__ __launch_bounds__(TB, 1) void fused_kernel(
        const float* __restrict__ xyz,  const float* __restrict__ points,
        const float* __restrict__ w1,   const float* __restrict__ b1,
        const float* __restrict__ w2,   const float* __restrict__ b2,
        const float* __restrict__ w3,   const float* __restrict__ b3,
        float* __restrict__ new_xyz, float* __restrict__ new_points,
        unsigned* flags, int far0, int far1) {
    __shared__ float4 s_slot[2 * NW];
    __shared__ unsigned short s_sidx[4 * NPTS];
    __shared__ __align__(16) float s_sh2[4 * 64 * 36];
    const int blk = blockIdx.x;
    const int tid = threadIdx.x;
    if (blk < 2) {
        const int bg = blk;
        fps_role<true>(xyz + (size_t)bg * NPTS * 3,
                       new_xyz + (size_t)bg * SOUT * 3,
                       flags + (bg << 6),
                       (bg == 0) ? far0 : far1,
                       s_slot, nullptr, tid);
    } else {
        const int lane = tid & 63;
        const int wvl  = tid >> 6;
        const int q    = (blk - 2) * 4 + wvl;     // 1024 queries
        group_role(xyz, points, w1, b1, w2, b2, w3, b3, new_xyz, new_points,
                   flags, s_sidx + wvl * NPTS, s_sh2 + wvl * 64 * 36, lane, q);
    }
}

// =================== fallback kernels (ws too small): serial R6 path =========
__global__ __launch_bounds__(TB, 1) void fps_kernel(const float* __restrict__ xyz,
                                                    float* __restrict__ new_xyz,
                                                    int far0, int far1) {
    __shared__ float4 s_slot[2 * NW];
    __shared__ __align__(16) float s_scf[SOUT * 3];
    const int bg = blockIdx.x;
    fps_role<false>(xyz + (size_t)bg * NPTS * 3, new_xyz + (size_t)bg * SOUT * 3,
                    nullptr, (bg == 0) ? far0 : far1, s_slot, s_scf, threadIdx.x);
}
__global__ __launch_bounds__(64, 1) void group_kernel(
        const float* __restrict__ xyz,  const float* __restrict__ points,
        const float* __restrict__ w1,   const float* __restrict__ b1,
        const float* __restrict__ w2,   const float* __restrict__ b2,
        const float* __restrict__ w3,   const float* __restrict__ b3,
        const float* __restrict__ new_xyz, float* __restrict__ new_points) {
    __shared__ unsigned short s_sidx[NPTS];
    __shared__ __align__(16) float s_sh2[64 * 36];
    group_role(xyz, points, w1, b1, w2, b2, w3, b3, new_xyz, new_points,
               nullptr, s_sidx, s_sh2, threadIdx.x, blockIdx.x);
}

// ---------------- host: threefry2x32 (JAX key(42) randint seed) --------------
static inline uint32_t rotl32(uint32_t x, int r) { return (x << r) | (x >> (32 - r)); }
static void threefry2x32_host(uint32_t k0, uint32_t k1, uint32_t& x0, uint32_t& x1) {
    const int R[2][4] = {{13,15,26,6},{17,29,16,24}};
    uint32_t ks[3] = {k0, k1, k0 ^ k1 ^ 0x1BD11BDAu};
    x0 += ks[0]; x1 += ks[1];
    for (int i = 0; i < 5; ++i) {
        for (int j = 0; j < 4; ++j) { x0 += x1; x1 = rotl32(x1, R[i & 1][j]); x1 ^= x0; }
        x0 += ks[(i + 1) % 3];
        x1 += ks[(i + 2) % 3] + (uint32_t)(i + 1);
    }
}

extern "C" void kernel_launch(void* const* d_in, const int* in_sizes, int n_in,
                              void* d_out, int out_size, void* d_ws, size_t ws_size,
                              hipStream_t stream) {
    const float* xyz    = (const float*)d_in[0];
    const float* points = (const float*)d_in[1];
    const float* w1 = (const float*)d_in[2];
    const float* b1 = (const float*)d_in[3];
    const float* w2 = (const float*)d_in[4];
    const float* b2 = (const float*)d_in[5];
    const float* w3 = (const float*)d_in[6];
    const float* b3 = (const float*)d_in[7];
    float* out        = (float*)d_out;
    float* new_xyz    = out;                      // (B, S, 3)
    float* new_points = out + NB * SOUT * 3;      // (B, 64, S)

    // jax.random.randint(key(42), (2,), 0, 2048), modern JAX
    // (jax_threefry_partitionable=True): _randint splits the key first:
    //   k1, k2 = split(key); result = random_bits(k2, 32, (2,)) & 2047
    // foldlike split: k2 = threefry((0,42),(0,1)) full pair.
    // partitionable bits: elem i = xor-halves of threefry(k2, (0,i)).
    // (VERIFIED passing in rounds 3-9 — do not change.)
    uint32_t k2a = 0, k2b = 1; threefry2x32_host(0u, 42u, k2a, k2b);
    uint32_t u0 = 0, u1 = 0;  threefry2x32_host(k2a, k2b, u0, u1);
    uint32_t v0 = 0, v1 = 1;  threefry2x32_host(k2a, k2b, v0, v1);
    int far0 = (int)((u0 ^ u1) & (NPTS - 1));
    int far1 = (int)((v0 ^ v1) & (NPTS - 1));

    if (ws_size >= 512) {
        // fused producer-consumer: flags in d_ws (poison 0xAAAAAAAA < FMAGIC
        // -> consumers spin until this launch's publisher writes).
        hipLaunchKernelGGL(fused_kernel, dim3(2 + NB * SOUT / 4), dim3(TB), 0, stream,
                           xyz, points, w1, b1, w2, b2, w3, b3,
                           new_xyz, new_points, (unsigned*)d_ws, far0, far1);
    } else {
        hipLaunchKernelGGL(fps_kernel, dim3(NB), dim3(TB), 0, stream,
                           xyz, new_xyz, far0, far1);
        hipLaunchKernelGGL(group_kernel, dim3(NB * SOUT), dim3(64), 0, stream,
                           xyz, points, w1, b1, w2, b2, w3, b3, new_xyz, new_points);
    }
}